// Round 11
// baseline (132.360 us; speedup 1.0000x reference)
//
#include <hip/hip_runtime.h>
#include <math.h>

// ============================================================================
// DIAGNOSTIC ROUND: kernel body is R10's mam_fused11, UNCHANGED (verified,
// absmax 0). kernel_launch fires it 5x back-to-back (idempotent: identical
// inputs -> identical outputs rewritten). Purpose: dur_5x - dur_1x = 4*kernel,
// canceling the harness offset (observed variance +-9us) that has made every
// single-launch dur_us reading ambiguous. R10 dur_1x = 71.5us.
//   kernel_time = (dur_us - 71.5) / 4
// ============================================================================

#define N_ 2048
#define K_ 512
#define J_ 256

typedef float f32x4 __attribute__((ext_vector_type(4)));
typedef __attribute__((address_space(3))) float       lds_f;
typedef const __attribute__((address_space(1))) float glb_f;

#define MAX3(acc, a, b) asm("v_max3_f32 %0, %0, %1, %2" : "+v"(acc) : "v"(a), "v"(b))
#define MIN3(acc, a, b) asm("v_min3_f32 %0, %0, %1, %2" : "+v"(acc) : "v"(a), "v"(b))

__global__ __launch_bounds__(512, 2) void mam_fused11(
    const float* __restrict__ x, const float* __restrict__ w,
    const float* __restrict__ bias, float* __restrict__ out)
{
    __shared__ __align__(16) float sm[24576];   // 96 KB: x[2][64][128] | w[2][32][128]

    const int t    = threadIdx.x;
    const int lane = t & 63;
    const int kq   = __builtin_amdgcn_readfirstlane(t >> 6);   // wave 0..7

    const int wg0 = (int)blockIdx.x;
    const int wg  = (wg0 & 7) * 32 + (wg0 >> 3);
    const int bx  = wg & 7;             // j-block (32 cols)
    const int by  = wg >> 3;            // n-block (64 rows)
    const int n0  = by * 64;
    const int j0  = bx * 32;

    const int rn = lane >> 3;           // 0..7
    const int cj = lane & 7;            // 0..7

    float mx[8][4], mn[8][4];
#pragma unroll
    for (int i = 0; i < 8; ++i)
#pragma unroll
        for (int jj = 0; jj < 4; ++jj) {
            mx[i][jj] = -__builtin_inff();
            mn[i][jj] =  __builtin_inff();
        }

#define STAGE(buf, s)                                                          \
    {                                                                          \
        const int kb = (s) * 128;                                              \
        _Pragma("unroll")                                                      \
        for (int u = 0; u < 4; ++u) {   /* x: 32 loads, 4 per wave */          \
            const int li  = kq * 4 + u;                                        \
            const int row = 2 * li + (lane >> 5);                              \
            __builtin_amdgcn_global_load_lds(                                  \
                (glb_f*)(x + (size_t)(n0 + row) * K_ + kb                      \
                         + (((lane & 31) ^ (row & 7)) << 2)),                  \
                (lds_f*)(sm + (buf) * 8192 + li * 256), 16, 0, 0);             \
        }                                                                      \
        _Pragma("unroll")                                                      \
        for (int u = 0; u < 2; ++u) {   /* w: 16 loads, 2 per wave */          \
            const int wi  = kq * 2 + u;                                        \
            const int col = 2 * wi + (lane >> 5);                              \
            __builtin_amdgcn_global_load_lds(                                  \
                (glb_f*)(w + (size_t)(j0 + col) * K_ + kb                      \
                         + (((lane & 31) ^ (col & 7)) << 2)),                  \
                (lds_f*)(sm + 16384 + (buf) * 4096 + wi * 256), 16, 0, 0);     \
        }                                                                      \
    }

    f32x4 AXv[8], AWv[4], BXv[8], BWv[4];   // double-buffered read sets

#define READQ(Xv, Wv, xa, wa, WCNT)                                            \
    asm volatile(                                                              \
        "ds_read_b128 %0, %12\n\t"                                             \
        "ds_read_b128 %1, %12 offset:4096\n\t"                                 \
        "ds_read_b128 %2, %12 offset:8192\n\t"                                 \
        "ds_read_b128 %3, %12 offset:12288\n\t"                                \
        "ds_read_b128 %4, %12 offset:16384\n\t"                                \
        "ds_read_b128 %5, %12 offset:20480\n\t"                                \
        "ds_read_b128 %6, %12 offset:24576\n\t"                                \
        "ds_read_b128 %7, %12 offset:28672\n\t"                                \
        "ds_read_b128 %8, %13\n\t"                                             \
        "ds_read_b128 %9, %13 offset:4096\n\t"                                 \
        "ds_read_b128 %10, %13 offset:8192\n\t"                                \
        "ds_read_b128 %11, %13 offset:12288\n\t"                               \
        WCNT                                                                   \
        : "=&v"(Xv[0]), "=&v"(Xv[1]), "=&v"(Xv[2]), "=&v"(Xv[3]),              \
          "=&v"(Xv[4]), "=&v"(Xv[5]), "=&v"(Xv[6]), "=&v"(Xv[7]),              \
          "=&v"(Wv[0]), "=&v"(Wv[1]), "=&v"(Wv[2]), "=&v"(Wv[3])               \
        : "v"(xa), "v"(wa));                                                   \
    __builtin_amdgcn_sched_barrier(0);

#define COMPQ(Xv, Wv)                                                          \
    _Pragma("unroll")                                                          \
    for (int i = 0; i < 8; ++i)                                                \
        _Pragma("unroll")                                                      \
        for (int jj = 0; jj < 4; ++jj) {                                       \
            const f32x4 a = Xv[i], b = Wv[jj];                                 \
            const float p0 = a.x * b.x, p1 = a.y * b.y;                        \
            const float p2 = a.z * b.z, p3 = a.w * b.w;                        \
            MAX3(mx[i][jj], p0, p1); MAX3(mx[i][jj], p2, p3);                  \
            MIN3(mn[i][jj], p0, p1); MIN3(mn[i][jj], p2, p3);                  \
        }

#define COMP(buf)                                                              \
    {                                                                          \
        const unsigned xb0 = (buf) * 32768u + (unsigned)(rn * 512);            \
        const unsigned wb0 = 65536u + (buf) * 16384u + (unsigned)(cj * 512);   \
        const unsigned xa0 = xb0 + (unsigned)((((kq * 4 + 0) ^ rn)) << 4);     \
        const unsigned wa0 = wb0 + (unsigned)((((kq * 4 + 0) ^ cj)) << 4);     \
        const unsigned xa1 = xb0 + (unsigned)((((kq * 4 + 1) ^ rn)) << 4);     \
        const unsigned wa1 = wb0 + (unsigned)((((kq * 4 + 1) ^ cj)) << 4);     \
        const unsigned xa2 = xb0 + (unsigned)((((kq * 4 + 2) ^ rn)) << 4);     \
        const unsigned wa2 = wb0 + (unsigned)((((kq * 4 + 2) ^ cj)) << 4);     \
        const unsigned xa3 = xb0 + (unsigned)((((kq * 4 + 3) ^ rn)) << 4);     \
        const unsigned wa3 = wb0 + (unsigned)((((kq * 4 + 3) ^ cj)) << 4);     \
        READQ(AXv, AWv, xa0, wa0, "");                                         \
        READQ(BXv, BWv, xa1, wa1, "s_waitcnt lgkmcnt(12)\n\t");                \
        COMPQ(AXv, AWv);                                                       \
        READQ(AXv, AWv, xa2, wa2, "s_waitcnt lgkmcnt(12)\n\t");                \
        COMPQ(BXv, BWv);                                                       \
        READQ(BXv, BWv, xa3, wa3, "s_waitcnt lgkmcnt(12)\n\t");                \
        COMPQ(AXv, AWv);                                                       \
        asm volatile("s_waitcnt lgkmcnt(0)");                                  \
        __builtin_amdgcn_sched_barrier(0);                                     \
        COMPQ(BXv, BWv);                                                       \
    }

    STAGE(0, 0);
    __syncthreads();
    STAGE(1, 1);  COMP(0);
    __syncthreads();
    STAGE(0, 2);  COMP(1);
    __syncthreads();
    STAGE(1, 3);  COMP(0);
    __syncthreads();
                  COMP(1);
    __syncthreads();   // LDS about to be reused for the combine

#undef STAGE
#undef READQ
#undef COMPQ
#undef COMP

    // ---- Combine 8 k-chunks, two 16-col halves (cb[8][64][17] float2 = 68KB).
    float2* cb = (float2*)sm;
#pragma unroll
    for (int h = 0; h < 2; ++h) {
#pragma unroll
        for (int i = 0; i < 8; ++i)
#pragma unroll
            for (int jh = 0; jh < 2; ++jh) {
                const int jj = 2 * h + jh;
                float2 v; v.x = mx[i][jj]; v.y = mn[i][jj];
                cb[(kq * 64 + rn + 8 * i) * 17 + cj + 8 * jh] = v;
            }
        __syncthreads();
#pragma unroll
        for (int e = 0; e < 2; ++e) {
            const int o   = t + e * 512;       // 1024 outputs per half
            const int row = o >> 4;
            const int c16 = o & 15;
            float a = -__builtin_inff(), b = __builtin_inff();
#pragma unroll
            for (int c = 0; c < 8; ++c) {
                const float2 v = cb[(c * 64 + row) * 17 + c16];
                a = fmaxf(a, v.x);
                b = fminf(b, v.y);
            }
            const int j = j0 + 16 * h + c16;
            out[(size_t)(n0 + row) * J_ + j] = a + b + bias[j];
        }
        __syncthreads();
    }
}

extern "C" void kernel_launch(void* const* d_in, const int* in_sizes, int n_in,
                              void* d_out, int out_size, void* d_ws, size_t ws_size,
                              hipStream_t stream) {
    const float* x    = (const float*)d_in[0];
    const float* w    = (const float*)d_in[1];
    const float* bias = (const float*)d_in[2];
    float* out = (float*)d_out;

    dim3 grid(256);   // 32 n-blocks x 8 j-blocks, XCD-swizzled in-kernel
    // DIAGNOSTIC: 5 identical launches (idempotent). kernel = (dur - 71.5)/4.
    for (int r = 0; r < 5; ++r)
        mam_fused11<<<grid, 512, 0, stream>>>(x, w, bias, out);
}

// Round 13
// 72.742 us; speedup vs baseline: 1.8196x; 1.8196x over previous
//
#include <hip/hip_runtime.h>
#include <math.h>

#define N_ 2048
#define K_ 512
#define J_ 256

typedef float f32x4 __attribute__((ext_vector_type(4)));
typedef float f32x2 __attribute__((ext_vector_type(2)));
typedef __attribute__((address_space(3))) float       lds_f;
typedef const __attribute__((address_space(1))) float glb_f;

#define MAX3(acc, a, b) asm("v_max3_f32 %0, %0, %1, %2" : "+v"(acc) : "v"(a), "v"(b))
#define MIN3(acc, a, b) asm("v_min3_f32 %0, %0, %1, %2" : "+v"(acc) : "v"(a), "v"(b))

// Grid 512 x 512 thr (8 waves), 64 KB LDS -> 2 blocks/CU, 16 waves/CU (4/SIMD).
// R11 diagnostic: kernel = 15.2us vs pipes DS 7.7 / VALU 6.8 -> main loop ran
// ~60% DS-utilized; residual = wait/barrier exposure at 1 block/CU. This
// version: block 32n x 32j, per-lane tile (4,4), so a SECOND resident block
// covers every lgkmcnt/barrier/staging stall. Pipeline skeleton is R10's
// (verified): per quad one asm block of 8 ds_read_b128 + counted lgkmcnt(8)
// (waits previous quad; DS in-order) + sched_barrier(0); A/B register sets.
// Products as float2 vector muls -> v_pk_mul_f32 (3 insts / 2 products).
// R12 BUGFIX: per-lane rows are rn+8i and row pitch is 512 B regardless of
// tile height -> READQ immediates are i*4096 B (R12 wrongly used i*2048,
// reading rows {rn,rn+4,rn+8,rn+12}; rows 20-31 were never read -> absmax .2).
__global__ __launch_bounds__(512, 4) void mam_fused12(
    const float* __restrict__ x, const float* __restrict__ w,
    const float* __restrict__ bias, float* __restrict__ out)
{
    __shared__ __align__(16) float sm[16384];   // 64 KB: x[2][32][128] | w[2][32][128]

    const int t    = threadIdx.x;
    const int lane = t & 63;
    const int kq   = __builtin_amdgcn_readfirstlane(t >> 6);   // wave 0..7

    // XCD-chunked bijective swizzle (512 = 8 * 64).
    const int wg0 = (int)blockIdx.x;
    const int wg  = (wg0 & 7) * 64 + (wg0 >> 3);
    const int bx  = wg & 7;             // j-block (32 cols)
    const int by  = wg >> 3;            // n-block (32 rows), 0..63
    const int n0  = by * 32;
    const int j0  = bx * 32;

    const int rn = lane >> 3;           // 0..7
    const int cj = lane & 7;            // 0..7

    float mx[4][4], mn[4][4];
#pragma unroll
    for (int i = 0; i < 4; ++i)
#pragma unroll
        for (int jj = 0; jj < 4; ++jj) {
            mx[i][jj] = -__builtin_inff();
            mn[i][jj] =  __builtin_inff();
        }

    // ---- Staging (R9/R10-verified row-pair pattern, used for BOTH tiles):
    // slice s = 128 k; element [row][k] at LDS slot (k>>2)^(row&7); linear
    // dest (gload_lds writes base + lane*16) + inverse-swizzled source.
#define STAGE(buf, s)                                                          \
    {                                                                          \
        const int kb = (s) * 128;                                              \
        _Pragma("unroll")                                                      \
        for (int u = 0; u < 2; ++u) {   /* x: 16 loads, 2 per wave */          \
            const int li  = kq * 2 + u;                                        \
            const int row = 2 * li + (lane >> 5);                              \
            __builtin_amdgcn_global_load_lds(                                  \
                (glb_f*)(x + (size_t)(n0 + row) * K_ + kb                      \
                         + (((lane & 31) ^ (row & 7)) << 2)),                  \
                (lds_f*)(sm + (buf) * 4096 + li * 256), 16, 0, 0);             \
        }                                                                      \
        _Pragma("unroll")                                                      \
        for (int u = 0; u < 2; ++u) {   /* w: 16 loads, 2 per wave */          \
            const int li  = kq * 2 + u;                                        \
            const int col = 2 * li + (lane >> 5);                              \
            __builtin_amdgcn_global_load_lds(                                  \
                (glb_f*)(w + (size_t)(j0 + col) * K_ + kb                      \
                         + (((lane & 31) ^ (col & 7)) << 2)),                  \
                (lds_f*)(sm + 8192 + (buf) * 4096 + li * 256), 16, 0, 0);      \
        }                                                                      \
    }

    f32x4 AX[4], AW[4], BX[4], BW[4];   // double-buffered read sets

    // One quad: 4 x-rows (rn+8i, +4096 B each) + 4 w-cols (cj+8jj, +4096 B);
    // counted wait for the PREVIOUS quad's 8 reads; fence (rule #18).
#define READQ(Xv, Wv, xa, wa, WCNT)                                            \
    asm volatile(                                                              \
        "ds_read_b128 %0, %8\n\t"                                              \
        "ds_read_b128 %1, %8 offset:4096\n\t"                                  \
        "ds_read_b128 %2, %8 offset:8192\n\t"                                  \
        "ds_read_b128 %3, %8 offset:12288\n\t"                                 \
        "ds_read_b128 %4, %9\n\t"                                              \
        "ds_read_b128 %5, %9 offset:4096\n\t"                                  \
        "ds_read_b128 %6, %9 offset:8192\n\t"                                  \
        "ds_read_b128 %7, %9 offset:12288\n\t"                                 \
        WCNT                                                                   \
        : "=&v"(Xv[0]), "=&v"(Xv[1]), "=&v"(Xv[2]), "=&v"(Xv[3]),              \
          "=&v"(Wv[0]), "=&v"(Wv[1]), "=&v"(Wv[2]), "=&v"(Wv[3])               \
        : "v"(xa), "v"(wa));                                                   \
    __builtin_amdgcn_sched_barrier(0);

    // float2 muls -> v_pk_mul_f32; max3/min3 on components.
#define COMPQ(Xv, Wv)                                                          \
    _Pragma("unroll")                                                          \
    for (int i = 0; i < 4; ++i)                                                \
        _Pragma("unroll")                                                      \
        for (int jj = 0; jj < 4; ++jj) {                                       \
            const f32x2 plo = Xv[i].lo * Wv[jj].lo;                            \
            const f32x2 phi = Xv[i].hi * Wv[jj].hi;                            \
            MAX3(mx[i][jj], plo.x, plo.y); MAX3(mx[i][jj], phi.x, phi.y);      \
            MIN3(mn[i][jj], plo.x, plo.y); MIN3(mn[i][jj], phi.x, phi.y);      \
        }

    // LDS byte addrs: x: buf*16384 + rn*512 + ((slot^rn)<<4)  (+i*4096 imm)
    //                 w: 32768 + buf*16384 + cj*512 + ((slot^cj)<<4) (+jj*4096)
#define COMP(buf)                                                              \
    {                                                                          \
        const unsigned xb0 = (buf) * 16384u + (unsigned)(rn * 512);            \
        const unsigned wb0 = 32768u + (buf) * 16384u + (unsigned)(cj * 512);   \
        const unsigned xa0 = xb0 + (unsigned)((((kq * 4 + 0) ^ rn)) << 4);     \
        const unsigned wa0 = wb0 + (unsigned)((((kq * 4 + 0) ^ cj)) << 4);     \
        const unsigned xa1 = xb0 + (unsigned)((((kq * 4 + 1) ^ rn)) << 4);     \
        const unsigned wa1 = wb0 + (unsigned)((((kq * 4 + 1) ^ cj)) << 4);     \
        const unsigned xa2 = xb0 + (unsigned)((((kq * 4 + 2) ^ rn)) << 4);     \
        const unsigned wa2 = wb0 + (unsigned)((((kq * 4 + 2) ^ cj)) << 4);     \
        const unsigned xa3 = xb0 + (unsigned)((((kq * 4 + 3) ^ rn)) << 4);     \
        const unsigned wa3 = wb0 + (unsigned)((((kq * 4 + 3) ^ cj)) << 4);     \
        READQ(AX, AW, xa0, wa0, "");                                           \
        READQ(BX, BW, xa1, wa1, "s_waitcnt lgkmcnt(8)\n\t");                   \
        COMPQ(AX, AW);                                                         \
        READQ(AX, AW, xa2, wa2, "s_waitcnt lgkmcnt(8)\n\t");                   \
        COMPQ(BX, BW);                                                         \
        READQ(BX, BW, xa3, wa3, "s_waitcnt lgkmcnt(8)\n\t");                   \
        COMPQ(AX, AW);                                                         \
        asm volatile("s_waitcnt lgkmcnt(0)");                                  \
        __builtin_amdgcn_sched_barrier(0);                                     \
        COMPQ(BX, BW);                                                         \
    }

    STAGE(0, 0);
    __syncthreads();
    STAGE(1, 1);  COMP(0);
    __syncthreads();
    STAGE(0, 2);  COMP(1);
    __syncthreads();
    STAGE(1, 3);  COMP(0);
    __syncthreads();
                  COMP(1);
    __syncthreads();   // LDS about to be reused for the combine

#undef STAGE
#undef READQ
#undef COMPQ
#undef COMP

    // ---- Combine 8 k-chunks, two 16-col halves (cb[8][32][17] float2 = 34.8KB).
    float2* cb = (float2*)sm;
#pragma unroll
    for (int h = 0; h < 2; ++h) {
#pragma unroll
        for (int i = 0; i < 4; ++i)
#pragma unroll
            for (int jh = 0; jh < 2; ++jh) {
                const int jj = 2 * h + jh;
                float2 v; v.x = mx[i][jj]; v.y = mn[i][jj];
                cb[(kq * 32 + rn + 8 * i) * 17 + cj + 8 * jh] = v;
            }
        __syncthreads();
        {
            const int row = t >> 4;        // 512 threads = 32 rows x 16 cols
            const int c16 = t & 15;
            float a = -__builtin_inff(), b = __builtin_inff();
#pragma unroll
            for (int c = 0; c < 8; ++c) {
                const float2 v = cb[(c * 32 + row) * 17 + c16];
                a = fmaxf(a, v.x);
                b = fminf(b, v.y);
            }
            const int j = j0 + 16 * h + c16;
            out[(size_t)(n0 + row) * J_ + j] = a + b + bias[j];
        }
        __syncthreads();
    }
}

extern "C" void kernel_launch(void* const* d_in, const int* in_sizes, int n_in,
                              void* d_out, int out_size, void* d_ws, size_t ws_size,
                              hipStream_t stream) {
    const float* x    = (const float*)d_in[0];
    const float* w    = (const float*)d_in[1];
    const float* bias = (const float*)d_in[2];
    float* out = (float*)d_out;

    dim3 grid(512);   // 64 n-blocks x 8 j-blocks, XCD-swizzled in-kernel
    mam_fused12<<<grid, 512, 0, stream>>>(x, w, bias, out);
}